// Round 4
// baseline (666.025 us; speedup 1.0000x reference)
//
#include <hip/hip_runtime.h>
#include <math.h>

// AlphaSegmenter: GNN encode (f64 path for exact Bernoulli decisions) ->
// Bernoulli threshold -> segmented carry scan -> decode MLP (f32) -> BCE loss.
// Outputs: [loss(1), logits(T*16), hard_alpha(T), hard_g(T*16)] as f32.
// R2: capped unrolling (decode spilled 6.7GB -> fixed, 4142->786us).
// R3: parallel preps + fused h-column-sums (786->470us).
// R4: h relayout [block][col][256] -> fully coalesced 512B/instr h traffic;
//     register-preload full s/a rows (8x float4 bursts) so each 128B line is
//     consumed while resident. Kills the 4-5x HBM amplification on h1.

#define TT 262144
#define NBT 1024   // TT/256 tile blocks
#define NBR 512    // reduction blocks for s,a

__device__ __forceinline__ double ls64(double x) {            // log sigmoid
  return fmin(x, 0.0) - log1p(exp(-fabs(x)));
}
__device__ __forceinline__ float spf32(float x) {             // softplus
  return fmaxf(x, 0.f) + log1pf(expf(-fabsf(x)));
}

// ---- deterministic column-sum: in [T,C] -> partials [NBR][C] (f64) ----
template <int C>
__global__ __launch_bounds__(256) void reduce_cols(const float* __restrict__ in,
                                                   double* __restrict__ part) {
  const int rpb = 256 / C;
  int col = threadIdx.x & (C - 1);
  int sub = threadIdx.x / C;
  long row0 = (long)blockIdx.x * rpb + sub;
  long stride = (long)NBR * rpb;
  double acc = 0.0;
  for (long r = row0; r < TT; r += stride) acc += (double)in[r * C + col];
  __shared__ double sm[256];
  sm[threadIdx.x] = acc;
  __syncthreads();
  if (threadIdx.x < C) {
    double s = 0.0;
#pragma unroll
    for (int i = 0; i < rpb; ++i) s += sm[i * C + threadIdx.x];  // fixed order
    part[(long)blockIdx.x * C + threadIdx.x] = s;
  }
}

// ---- c1 = b1 + mean_x @ W1[80:160]; parallel tree over [512][64|16] ----
__global__ __launch_bounds__(640) void prep1(const double* __restrict__ ps_s,
                                             const double* __restrict__ ps_a,
                                             const float* __restrict__ W1,
                                             const float* __restrict__ b1,
                                             double invT, double* __restrict__ c1) {
  __shared__ double partial[80][8];
  __shared__ double mx[80];
  int tid = threadIdx.x;
  int col = tid >> 3, sub = tid & 7;   // 80 cols x 8 threads
  double ssum = 0.0;
  if (col < 64) {
#pragma unroll
    for (int i = 0; i < 64; ++i) ssum += ps_s[(sub * 64 + i) * 64 + col];
  } else {
    int c = col - 64;
#pragma unroll
    for (int i = 0; i < 64; ++i) ssum += ps_a[(sub * 64 + i) * 16 + c];
  }
  partial[col][sub] = ssum;
  __syncthreads();
  if (tid < 80) {
    double s = 0.0;
#pragma unroll
    for (int i = 0; i < 8; ++i) s += partial[tid][i];  // fixed order
    mx[tid] = s * invT;
  }
  __syncthreads();
  if (tid < 32) {
    double acc = (double)b1[tid];
#pragma unroll 8
    for (int j = 0; j < 80; ++j) acc += mx[j] * (double)W1[(80 + j) * 32 + tid];
    c1[tid] = acc;
  }
}

// ---- c2 = b2 + mean_h1 @ W2[32:64]; parallel tree over [1024][32] ----
__global__ __launch_bounds__(256) void prep2(const double* __restrict__ ps,
                                             const float* __restrict__ W2,
                                             const float* __restrict__ b2,
                                             double invT, double* __restrict__ c2) {
  __shared__ double partial[32][8];
  __shared__ double mh[32];
  int tid = threadIdx.x;
  int col = tid >> 3, sub = tid & 7;   // 32 cols x 8 threads, 128 each
  double ssum = 0.0;
#pragma unroll
  for (int i = 0; i < 128; ++i) ssum += ps[(sub * 128 + i) * 32 + col];
  partial[col][sub] = ssum;
  __syncthreads();
  if (tid < 32) {
    double s = 0.0;
#pragma unroll
    for (int i = 0; i < 8; ++i) s += partial[tid][i];
    mh[tid] = s * invT;
  }
  __syncthreads();
  if (tid < 32) {
    double acc = (double)b2[tid];
#pragma unroll 8
    for (int j = 0; j < 32; ++j) acc += mh[j] * (double)W2[(32 + j) * 32 + tid];
    c2[tid] = acc;
  }
}

// ---- c3[k] = b3[32+k] + mean_h2 @ W3[32:64, 32+k], k=0..16 ----
__global__ __launch_bounds__(256) void prep3(const double* __restrict__ ps,
                                             const float* __restrict__ W3,
                                             const float* __restrict__ b3,
                                             double invT, double* __restrict__ c3) {
  __shared__ double partial[32][8];
  __shared__ double mh[32];
  int tid = threadIdx.x;
  int col = tid >> 3, sub = tid & 7;
  double ssum = 0.0;
#pragma unroll
  for (int i = 0; i < 128; ++i) ssum += ps[(sub * 128 + i) * 32 + col];
  partial[col][sub] = ssum;
  __syncthreads();
  if (tid < 32) {
    double s = 0.0;
#pragma unroll
    for (int i = 0; i < 8; ++i) s += partial[tid][i];
    mh[tid] = s * invT;
  }
  __syncthreads();
  if (tid < 17) {
    double acc = (double)b3[32 + tid];
#pragma unroll 8
    for (int j = 0; j < 32; ++j) acc += mh[j] * (double)W3[(32 + j) * 49 + 32 + tid];
    c3[tid] = acc;
  }
}

// ---- block-level column sum of o[32] via wave butterfly, fixed order ----
__device__ __forceinline__ void block_colsum32(const double* o, double* ws /*[4*32] LDS*/,
                                               double* part_out, int bid) {
  int lane = threadIdx.x & 63, wave = threadIdx.x >> 6;
#pragma unroll 4
  for (int k = 0; k < 32; ++k) {
    double v = o[k];
#pragma unroll
    for (int off = 32; off > 0; off >>= 1) v += __shfl_down(v, off, 64);
    if (lane == 0) ws[wave * 32 + k] = v;
  }
  __syncthreads();
  if (threadIdx.x < 32) {
    double s = ws[threadIdx.x] + ws[32 + threadIdx.x] + ws[64 + threadIdx.x] +
               ws[96 + threadIdx.x];
    part_out[bid * 32 + threadIdx.x] = s;
  }
}

// h relayout: element (block, col k, row r in 0..255) at h[(block*32+k)*256 + r]

// ---- h1 = tanh([s,a] @ W1[:80] + c1), f64; emits per-block col sums ----
__global__ __launch_bounds__(256, 3) void h1_kernel(const float* __restrict__ s,
                                                    const float* __restrict__ a,
                                                    const float* __restrict__ W1,
                                                    const double* __restrict__ c1,
                                                    double* __restrict__ h,
                                                    double* __restrict__ ps_h) {
  __shared__ double Wl[80 * 32];
  __shared__ double ws[4 * 32];
  for (int i = threadIdx.x; i < 80 * 32; i += 256) Wl[i] = (double)W1[i];
  __syncthreads();
  long t = (long)blockIdx.x * 256 + threadIdx.x;
  double acc[32];
#pragma unroll
  for (int k = 0; k < 32; ++k) acc[k] = c1[k];
  const float4* s4 = (const float4*)(s + t * 64);
  const float4* a4 = (const float4*)(a + t * 16);
  {
    float4 av[4];
#pragma unroll
    for (int q = 0; q < 4; ++q) av[q] = a4[q];     // 64B burst, line fully used
#pragma unroll
    for (int q = 0; q < 4; ++q) {
      const double* w = &Wl[(64 + q * 4) * 32];
      double x0 = (double)av[q].x, x1 = (double)av[q].y;
      double x2 = (double)av[q].z, x3 = (double)av[q].w;
#pragma unroll
      for (int k = 0; k < 32; ++k)
        acc[k] += x0 * w[k] + x1 * w[32 + k] + x2 * w[64 + k] + x3 * w[96 + k];
    }
  }
#pragma unroll
  for (int half = 0; half < 2; ++half) {
    float4 sv[8];
#pragma unroll
    for (int q = 0; q < 8; ++q) sv[q] = s4[half * 8 + q];  // 128B burst
#pragma unroll
    for (int q = 0; q < 8; ++q) {
      const double* w = &Wl[(half * 32 + q * 4) * 32];
      double x0 = (double)sv[q].x, x1 = (double)sv[q].y;
      double x2 = (double)sv[q].z, x3 = (double)sv[q].w;
#pragma unroll
      for (int k = 0; k < 32; ++k)
        acc[k] += x0 * w[k] + x1 * w[32 + k] + x2 * w[64 + k] + x3 * w[96 + k];
    }
  }
  double* o = h + (size_t)blockIdx.x * 32 * 256 + threadIdx.x;
#pragma unroll 4
  for (int k = 0; k < 32; ++k) { acc[k] = tanh(acc[k]); o[k * 256] = acc[k]; }
  block_colsum32(acc, ws, ps_h, blockIdx.x);
}

// ---- h2 = tanh(h1 @ W2[:32] + c2), f64, IN PLACE (own region); col sums ----
__global__ __launch_bounds__(256, 4) void h2_kernel(const double* __restrict__ hin,
                                                    const float* __restrict__ W2,
                                                    const double* __restrict__ c2,
                                                    double* __restrict__ hout,
                                                    double* __restrict__ ps_h) {
  __shared__ double Wl[32 * 32];
  __shared__ double ws[4 * 32];
  for (int i = threadIdx.x; i < 32 * 32; i += 256) Wl[i] = (double)W2[i];
  __syncthreads();
  const double* x = hin + (size_t)blockIdx.x * 32 * 256 + threadIdx.x;
  double acc[32];
#pragma unroll
  for (int k = 0; k < 32; ++k) acc[k] = c2[k];
#pragma unroll 4
  for (int j = 0; j < 32; ++j) {
    double xj = x[j * 256];                 // 512B coalesced per wave
#pragma unroll
    for (int k = 0; k < 32; ++k) acc[k] += xj * Wl[j * 32 + k];
  }
  double* o = hout + (size_t)blockIdx.x * 32 * 256 + threadIdx.x;
#pragma unroll 4
  for (int k = 0; k < 32; ++k) { acc[k] = tanh(acc[k]); o[k * 256] = acc[k]; }
  block_colsum32(acc, ws, ps_h, blockIdx.x);
}

// ---- g, alpha, hard_alpha, per-block last-fired, logprob partials ----
__global__ __launch_bounds__(256, 2) void out_kernel(const double* __restrict__ h,
                                                     const float* __restrict__ W3,
                                                     const double* __restrict__ c3,
                                                     const float* __restrict__ u,
                                                     float* __restrict__ g, float* __restrict__ ha,
                                                     int* __restrict__ lastf,
                                                     double* __restrict__ lp_part) {
  __shared__ double Wl[32 * 17];
  __shared__ double sm[256];
  __shared__ unsigned long long wm[4];
  for (int i = threadIdx.x; i < 32 * 17; i += 256) {
    int j = i / 17, k = i - j * 17;
    Wl[i] = (double)W3[j * 49 + 32 + k];
  }
  __syncthreads();
  long t = (long)blockIdx.x * 256 + threadIdx.x;
  const double* x = h + (size_t)blockIdx.x * 32 * 256 + threadIdx.x;
  double acc[17];
#pragma unroll
  for (int k = 0; k < 17; ++k) acc[k] = c3[k];
#pragma unroll 4
  for (int j = 0; j < 32; ++j) {
    double xj = x[j * 256];                 // 512B coalesced per wave
#pragma unroll
    for (int k = 0; k < 17; ++k) acc[k] += xj * Wl[j * 17 + k];
  }
  float4* g4 = (float4*)(g + t * 16);
  float4 o0, o1, o2, o3;
  o0.x = (float)acc[0];  o0.y = (float)acc[1];  o0.z = (float)acc[2];  o0.w = (float)acc[3];
  o1.x = (float)acc[4];  o1.y = (float)acc[5];  o1.z = (float)acc[6];  o1.w = (float)acc[7];
  o2.x = (float)acc[8];  o2.y = (float)acc[9];  o2.z = (float)acc[10]; o2.w = (float)acc[11];
  o3.x = (float)acc[12]; o3.y = (float)acc[13]; o3.z = (float)acc[14]; o3.w = (float)acc[15];
  g4[0] = o0; g4[1] = o1; g4[2] = o2; g4[3] = o3;
  double l = acc[16];
  double alpha = 1.0 / (1.0 + exp(-l));
  bool fired = ((double)u[t]) < alpha;
  ha[t] = fired ? 1.f : 0.f;
  sm[threadIdx.x] = fired ? ls64(l) : ls64(-l);
  unsigned long long bm = __ballot(fired ? 1 : 0);
  if ((threadIdx.x & 63) == 0) wm[threadIdx.x >> 6] = bm;
  __syncthreads();
  for (int off = 128; off > 0; off >>= 1) {
    if (threadIdx.x < off) sm[threadIdx.x] += sm[threadIdx.x + off];
    __syncthreads();
  }
  if (threadIdx.x == 0) {
    lp_part[blockIdx.x] = sm[0];
    int last = -1;
#pragma unroll
    for (int w = 3; w >= 0; --w) {
      if (last < 0 && wm[w])
        last = (int)((long)blockIdx.x * 256 + w * 64 + (63 - __builtin_clzll(wm[w])));
    }
    lastf[blockIdx.x] = last;
  }
}

// ---- exclusive max-scan over per-block last-fired indices ----
__global__ __launch_bounds__(1024) void carry_scan(const int* __restrict__ lastf,
                                                   int* __restrict__ carry, int n) {
  __shared__ int sm[1024];
  int tid = threadIdx.x;
  sm[tid] = (tid < n) ? lastf[tid] : -1;
  __syncthreads();
  for (int off = 1; off < n; off <<= 1) {
    int v = sm[tid];
    int o = (tid >= off) ? sm[tid - off] : -1;
    __syncthreads();
    sm[tid] = v > o ? v : o;
    __syncthreads();
  }
  if (tid < n) carry[tid] = (tid == 0) ? -1 : sm[tid - 1];
}

// ---- scan-combine, hard_g gather, decode MLP, logits, BCE partials ----
__global__ __launch_bounds__(256, 2) void decode_kernel(
    const float* __restrict__ s, const float* __restrict__ a, const float* __restrict__ g,
    const float* __restrict__ Wp1, const float* __restrict__ bp1, const float* __restrict__ Wp2,
    const float* __restrict__ bp2, const float* __restrict__ ha, const int* __restrict__ carry,
    float* __restrict__ logits, float* __restrict__ hardg, double* __restrict__ rc_part) {
  __shared__ float W1l[80 * 32];
  __shared__ float W2l[32 * 16];
  __shared__ int wlast[4];
  __shared__ double sm[256];
  long t = (long)blockIdx.x * 256 + threadIdx.x;
  bool fired = ha[t] > 0.5f;
  unsigned long long m = __ballot(fired ? 1 : 0);
  int wave = threadIdx.x >> 6, lane = threadIdx.x & 63;
  if (lane == 0)
    wlast[wave] = m ? (int)((long)blockIdx.x * 256 + wave * 64 + (63 - __builtin_clzll(m))) : -1;
  for (int i = threadIdx.x; i < 80 * 32; i += 256) W1l[i] = Wp1[i];
  for (int i = threadIdx.x; i < 32 * 16; i += 256) W2l[i] = Wp2[i];
  __syncthreads();
  unsigned long long pm = m & (~0ULL >> (63 - lane));
  int idx = pm ? (int)((long)blockIdx.x * 256 + wave * 64 + (63 - __builtin_clzll(pm))) : -1;
#pragma unroll
  for (int w = 0; w < 4; ++w)
    if (w < wave && wlast[w] > idx) idx = wlast[w];
  int cr = carry[blockIdx.x];
  if (cr > idx) idx = cr;
  float hg[16];
  if (idx >= 0) {
    const float4* g4 = (const float4*)(g + (long)idx * 16);
    float4 v0 = g4[0], v1 = g4[1], v2 = g4[2], v3 = g4[3];
    hg[0] = v0.x; hg[1] = v0.y; hg[2] = v0.z; hg[3] = v0.w;
    hg[4] = v1.x; hg[5] = v1.y; hg[6] = v1.z; hg[7] = v1.w;
    hg[8] = v2.x; hg[9] = v2.y; hg[10] = v2.z; hg[11] = v2.w;
    hg[12] = v3.x; hg[13] = v3.y; hg[14] = v3.z; hg[15] = v3.w;
  } else {
#pragma unroll
    for (int k = 0; k < 16; ++k) hg[k] = 0.f;
  }
#pragma unroll 4
  for (int k = 0; k < 16; ++k) hardg[t * 16 + k] = hg[k];   // d_out+… is 4B aligned only
  float acc[32];
#pragma unroll
  for (int k = 0; k < 32; ++k) acc[k] = bp1[k];
  const float4* s4 = (const float4*)(s + t * 64);
#pragma unroll
  for (int half = 0; half < 2; ++half) {
    float4 sv[8];
#pragma unroll
    for (int q = 0; q < 8; ++q) sv[q] = s4[half * 8 + q];  // 128B burst
#pragma unroll
    for (int q = 0; q < 8; ++q) {
      const float* w = &W1l[(half * 32 + q * 4) * 32];
#pragma unroll
      for (int k = 0; k < 32; ++k)
        acc[k] += sv[q].x * w[k] + sv[q].y * w[32 + k] + sv[q].z * w[64 + k] +
                  sv[q].w * w[96 + k];
    }
  }
#pragma unroll 4
  for (int j = 0; j < 16; ++j) {
    float xj = hg[j];
    const float* w = &W1l[(64 + j) * 32];
#pragma unroll
    for (int k = 0; k < 32; ++k) acc[k] += xj * w[k];
  }
#pragma unroll 4
  for (int k = 0; k < 32; ++k) acc[k] = tanhf(acc[k]);
  float lg[16];
#pragma unroll
  for (int k = 0; k < 16; ++k) lg[k] = bp2[k];
#pragma unroll 4
  for (int j = 0; j < 32; ++j) {
    float hj = acc[j];
    const float* w = &W2l[j * 16];
#pragma unroll
    for (int k = 0; k < 16; ++k) lg[k] += hj * w[k];
  }
#pragma unroll 4
  for (int k = 0; k < 16; ++k) logits[t * 16 + k] = lg[k];
  const float4* a4 = (const float4*)(a + t * 16);
  float4 av[4];
#pragma unroll
  for (int q = 0; q < 4; ++q) av[q] = a4[q];   // 64B burst
  double rs = 0.0;
#pragma unroll 2
  for (int q = 0; q < 4; ++q) {
    float l0 = lg[q * 4], l1 = lg[q * 4 + 1], l2 = lg[q * 4 + 2], l3 = lg[q * 4 + 3];
    rs += (double)(av[q].x * spf32(-l0) + (1.f - av[q].x) * spf32(l0));
    rs += (double)(av[q].y * spf32(-l1) + (1.f - av[q].y) * spf32(l1));
    rs += (double)(av[q].z * spf32(-l2) + (1.f - av[q].z) * spf32(l2));
    rs += (double)(av[q].w * spf32(-l3) + (1.f - av[q].w) * spf32(l3));
  }
  sm[threadIdx.x] = rs;
  __syncthreads();
  for (int off = 128; off > 0; off >>= 1) {
    if (threadIdx.x < off) sm[threadIdx.x] += sm[threadIdx.x + off];
    __syncthreads();
  }
  if (threadIdx.x == 0) rc_part[blockIdx.x] = sm[0];
}

// ---- loss = mean(recon) * (1 + mean(log_probs)) ----
__global__ __launch_bounds__(256) void finalize(const double* __restrict__ lp_part,
                                                const double* __restrict__ rc_part, int nb,
                                                double invT, float* __restrict__ out0) {
  __shared__ double s1[256], s2[256];
  int tid = threadIdx.x;
  double a1 = 0, a2 = 0;
  for (int i = tid; i < nb; i += 256) { a1 += lp_part[i]; a2 += rc_part[i]; }
  s1[tid] = a1; s2[tid] = a2;
  __syncthreads();
  for (int off = 128; off > 0; off >>= 1) {
    if (tid < off) { s1[tid] += s1[tid + off]; s2[tid] += s2[tid + off]; }
    __syncthreads();
  }
  if (tid == 0) {
    double R = s1[0] * invT;            // mean log_probs over T
    double M = s2[0] * invT / 16.0;     // mean recon over T*16
    out0[0] = (float)(M + R * M);
  }
}

extern "C" void kernel_launch(void* const* d_in, const int* in_sizes, int n_in,
                              void* d_out, int out_size, void* d_ws, size_t ws_size,
                              hipStream_t stream) {
  const float* s   = (const float*)d_in[0];
  const float* a   = (const float*)d_in[1];
  const float* u   = (const float*)d_in[2];
  const float* W1  = (const float*)d_in[3];
  const float* b1  = (const float*)d_in[4];
  const float* W2  = (const float*)d_in[5];
  const float* b2  = (const float*)d_in[6];
  const float* W3  = (const float*)d_in[7];
  const float* b3  = (const float*)d_in[8];
  const float* Wp1 = (const float*)d_in[9];
  const float* bp1 = (const float*)d_in[10];
  const float* Wp2 = (const float*)d_in[11];
  const float* bp2 = (const float*)d_in[12];

  const double invT = 1.0 / (double)TT;

  // workspace carve (f64 first for alignment)
  double* h      = (double*)d_ws;                 // TT*32 (relayout, h1 then h2)
  double* ps_s   = h + (size_t)TT * 32;           // NBR*64
  double* ps_a   = ps_s + (size_t)NBR * 64;       // NBR*16
  double* ps_h   = ps_a + (size_t)NBR * 16;       // NBT*32 (h1 partials, then h2)
  double* c1     = ps_h + (size_t)NBT * 32;       // 32
  double* c2     = c1 + 32;                       // 32
  double* c3     = c2 + 32;                       // 24 (17 used)
  double* lp_part= c3 + 24;                       // NBT
  double* rc_part= lp_part + NBT;                 // NBT
  float*  g      = (float*)(rc_part + NBT);       // TT*16
  int*    lastf  = (int*)(g + (size_t)TT * 16);   // NBT
  int*    carry  = lastf + NBT;                   // NBT

  float* out    = (float*)d_out;
  float* loss   = out;
  float* logits = out + 1;
  float* ha     = out + 1 + (size_t)TT * 16;
  float* hg     = ha + TT;

  reduce_cols<64><<<NBR, 256, 0, stream>>>(s, ps_s);
  reduce_cols<16><<<NBR, 256, 0, stream>>>(a, ps_a);
  prep1<<<1, 640, 0, stream>>>(ps_s, ps_a, W1, b1, invT, c1);
  h1_kernel<<<NBT, 256, 0, stream>>>(s, a, W1, c1, h, ps_h);
  prep2<<<1, 256, 0, stream>>>(ps_h, W2, b2, invT, c2);
  h2_kernel<<<NBT, 256, 0, stream>>>(h, W2, c2, h, ps_h);
  prep3<<<1, 256, 0, stream>>>(ps_h, W3, b3, invT, c3);
  out_kernel<<<NBT, 256, 0, stream>>>(h, W3, c3, u, g, ha, lastf, lp_part);
  carry_scan<<<1, NBT, 0, stream>>>(lastf, carry, NBT);
  decode_kernel<<<NBT, 256, 0, stream>>>(s, a, g, Wp1, bp1, Wp2, bp2, ha, carry,
                                         logits, hg, rc_part);
  finalize<<<1, 256, 0, stream>>>(lp_part, rc_part, NBT, invT, loss);
}

// Round 5
// 578.029 us; speedup vs baseline: 1.1522x; 1.1522x over previous
//
#include <hip/hip_runtime.h>
#include <math.h>

// AlphaSegmenter: GNN encode (f64 path for exact Bernoulli decisions) ->
// Bernoulli threshold -> segmented carry scan -> decode MLP (f32) -> BCE loss.
// Outputs: [loss(1), logits(T*16), hard_alpha(T), hard_g(T*16)] as f32.
// R2: capped unrolling (decode spilled 6.7GB -> 786us).
// R3: parallel preps + fused h-column-sums (786->470us).
// R4: h relayout [block][col][256] (coalesced) but WRITE exploded to 1GB.
// R5: root cause = acc[] register arrays demoted to scratch (VGPR_Count=56 <
//     64 needed for acc alone): runtime-indexed partial unrolls + OCML f64
//     tanh calls. Fix: full unroll of ALL register-array loops + inline
//     exp64-based tanh/sigmoid (no OCML f64 calls anywhere).

#define TT 262144
#define NBT 1024   // TT/256 tile blocks
#define NBR 512    // reduction blocks for s,a

__device__ __forceinline__ float spf32(float x) {             // softplus f32
  return fmaxf(x, 0.f) + log1pf(expf(-fabsf(x)));
}

// ---- inline f64 exp: Cody-Waite + degree-12 Horner, |x| <= 700 ----
__device__ __forceinline__ double exp64(double x) {
  const double LOG2E  = 1.4426950408889634074;
  const double LN2_HI = 6.93147180369123816490e-01;
  const double LN2_LO = 1.90821492927058770002e-10;
  double kd = rint(x * LOG2E);
  double r  = fma(-kd, LN2_HI, x);
  r = fma(-kd, LN2_LO, r);
  double p = 2.08767569878681e-9;                 // 1/12!
  p = fma(p, r, 2.505210838544172e-8);            // 1/11!
  p = fma(p, r, 2.755731922398589e-7);            // 1/10!
  p = fma(p, r, 2.7557319223985893e-6);           // 1/9!
  p = fma(p, r, 2.48015873015873e-5);             // 1/8!
  p = fma(p, r, 1.984126984126984e-4);            // 1/7!
  p = fma(p, r, 1.388888888888889e-3);            // 1/6!
  p = fma(p, r, 8.333333333333333e-3);            // 1/5!
  p = fma(p, r, 4.1666666666666664e-2);           // 1/4!
  p = fma(p, r, 1.6666666666666666e-1);           // 1/3!
  p = fma(p, r, 0.5);
  p = fma(p, r, 1.0);
  p = fma(p, r, 1.0);
  int k = (int)kd;
  long long sb = ((long long)(k + 1023)) << 52;   // 2^k
  return p * __longlong_as_double(sb);
}

__device__ __forceinline__ double tanh64(double x) {
  double ax = fmin(fabs(x), 19.0);                // tanh(19) rounds to <1ulp of 1
  double e = exp64(2.0 * ax);
  double t = 1.0 - 2.0 / (e + 1.0);
  return x >= 0.0 ? t : -t;
}

// ---- deterministic column-sum: in [T,C] -> partials [NBR][C] (f64) ----
template <int C>
__global__ __launch_bounds__(256) void reduce_cols(const float* __restrict__ in,
                                                   double* __restrict__ part) {
  const int rpb = 256 / C;
  int col = threadIdx.x & (C - 1);
  int sub = threadIdx.x / C;
  long row0 = (long)blockIdx.x * rpb + sub;
  long stride = (long)NBR * rpb;
  double acc = 0.0;
  for (long r = row0; r < TT; r += stride) acc += (double)in[r * C + col];
  __shared__ double sm[256];
  sm[threadIdx.x] = acc;
  __syncthreads();
  if (threadIdx.x < C) {
    double s = 0.0;
#pragma unroll
    for (int i = 0; i < rpb; ++i) s += sm[i * C + threadIdx.x];  // fixed order
    part[(long)blockIdx.x * C + threadIdx.x] = s;
  }
}

// ---- c1 = b1 + mean_x @ W1[80:160]; parallel tree over [512][64|16] ----
__global__ __launch_bounds__(640) void prep1(const double* __restrict__ ps_s,
                                             const double* __restrict__ ps_a,
                                             const float* __restrict__ W1,
                                             const float* __restrict__ b1,
                                             double invT, double* __restrict__ c1) {
  __shared__ double partial[80][8];
  __shared__ double mx[80];
  int tid = threadIdx.x;
  int col = tid >> 3, sub = tid & 7;   // 80 cols x 8 threads
  double ssum = 0.0;
  if (col < 64) {
#pragma unroll
    for (int i = 0; i < 64; ++i) ssum += ps_s[(sub * 64 + i) * 64 + col];
  } else {
    int c = col - 64;
#pragma unroll
    for (int i = 0; i < 64; ++i) ssum += ps_a[(sub * 64 + i) * 16 + c];
  }
  partial[col][sub] = ssum;
  __syncthreads();
  if (tid < 80) {
    double s = 0.0;
#pragma unroll
    for (int i = 0; i < 8; ++i) s += partial[tid][i];  // fixed order
    mx[tid] = s * invT;
  }
  __syncthreads();
  if (tid < 32) {
    double acc = (double)b1[tid];
    for (int j = 0; j < 80; ++j) acc += mx[j] * (double)W1[(80 + j) * 32 + tid];
    c1[tid] = acc;
  }
}

// ---- c2 = b2 + mean_h1 @ W2[32:64]; parallel tree over [1024][32] ----
__global__ __launch_bounds__(256) void prep2(const double* __restrict__ ps,
                                             const float* __restrict__ W2,
                                             const float* __restrict__ b2,
                                             double invT, double* __restrict__ c2) {
  __shared__ double partial[32][8];
  __shared__ double mh[32];
  int tid = threadIdx.x;
  int col = tid >> 3, sub = tid & 7;   // 32 cols x 8 threads, 128 each
  double ssum = 0.0;
#pragma unroll
  for (int i = 0; i < 128; ++i) ssum += ps[(sub * 128 + i) * 32 + col];
  partial[col][sub] = ssum;
  __syncthreads();
  if (tid < 32) {
    double s = 0.0;
#pragma unroll
    for (int i = 0; i < 8; ++i) s += partial[tid][i];
    mh[tid] = s * invT;
  }
  __syncthreads();
  if (tid < 32) {
    double acc = (double)b2[tid];
    for (int j = 0; j < 32; ++j) acc += mh[j] * (double)W2[(32 + j) * 32 + tid];
    c2[tid] = acc;
  }
}

// ---- c3[k] = b3[32+k] + mean_h2 @ W3[32:64, 32+k], k=0..16 ----
__global__ __launch_bounds__(256) void prep3(const double* __restrict__ ps,
                                             const float* __restrict__ W3,
                                             const float* __restrict__ b3,
                                             double invT, double* __restrict__ c3) {
  __shared__ double partial[32][8];
  __shared__ double mh[32];
  int tid = threadIdx.x;
  int col = tid >> 3, sub = tid & 7;
  double ssum = 0.0;
#pragma unroll
  for (int i = 0; i < 128; ++i) ssum += ps[(sub * 128 + i) * 32 + col];
  partial[col][sub] = ssum;
  __syncthreads();
  if (tid < 32) {
    double s = 0.0;
#pragma unroll
    for (int i = 0; i < 8; ++i) s += partial[tid][i];
    mh[tid] = s * invT;
  }
  __syncthreads();
  if (tid < 17) {
    double acc = (double)b3[32 + tid];
    for (int j = 0; j < 32; ++j) acc += mh[j] * (double)W3[(32 + j) * 49 + 32 + tid];
    c3[tid] = acc;
  }
}

// h layout: element (block b, col k, row r in 0..255) at h[b*8192 + k*256 + r]

// ---- h1 = tanh([s,a] @ W1[:80] + c1), f64; emits per-block col sums ----
__global__ __launch_bounds__(256, 2) void h1_kernel(const float* __restrict__ s,
                                                    const float* __restrict__ a,
                                                    const float* __restrict__ W1,
                                                    const double* __restrict__ c1,
                                                    double* __restrict__ h,
                                                    double* __restrict__ ps_h) {
  __shared__ double Wl[80 * 32];
  __shared__ double ws[4 * 32];
  for (int i = threadIdx.x; i < 80 * 32; i += 256) Wl[i] = (double)W1[i];
  __syncthreads();
  long t = (long)blockIdx.x * 256 + threadIdx.x;
  double acc[32];
#pragma unroll
  for (int k = 0; k < 32; ++k) acc[k] = c1[k];
  const float4* s4 = (const float4*)(s + t * 64);
#pragma unroll 2
  for (int q = 0; q < 16; ++q) {
    float4 v = s4[q];
    const double* w = &Wl[(q * 4) * 32];
    double x0 = (double)v.x, x1 = (double)v.y, x2 = (double)v.z, x3 = (double)v.w;
#pragma unroll
    for (int k = 0; k < 32; ++k)
      acc[k] += x0 * w[k] + x1 * w[32 + k] + x2 * w[64 + k] + x3 * w[96 + k];
  }
  const float4* a4 = (const float4*)(a + t * 16);
#pragma unroll 2
  for (int q = 0; q < 4; ++q) {
    float4 v = a4[q];
    const double* w = &Wl[(64 + q * 4) * 32];
    double x0 = (double)v.x, x1 = (double)v.y, x2 = (double)v.z, x3 = (double)v.w;
#pragma unroll
    for (int k = 0; k < 32; ++k)
      acc[k] += x0 * w[k] + x1 * w[32 + k] + x2 * w[64 + k] + x3 * w[96 + k];
  }
  double* o = h + (size_t)blockIdx.x * 8192 + threadIdx.x;
#pragma unroll
  for (int k = 0; k < 32; ++k) { acc[k] = tanh64(acc[k]); o[k * 256] = acc[k]; }
  int lane = threadIdx.x & 63, wave = threadIdx.x >> 6;
#pragma unroll
  for (int k = 0; k < 32; ++k) {
    double v = acc[k];
    v += __shfl_down(v, 32, 64); v += __shfl_down(v, 16, 64);
    v += __shfl_down(v, 8, 64);  v += __shfl_down(v, 4, 64);
    v += __shfl_down(v, 2, 64);  v += __shfl_down(v, 1, 64);
    if (lane == 0) ws[wave * 32 + k] = v;
  }
  __syncthreads();
  if (threadIdx.x < 32) {
    double ssum = ws[threadIdx.x] + ws[32 + threadIdx.x] + ws[64 + threadIdx.x] +
                  ws[96 + threadIdx.x];
    ps_h[blockIdx.x * 32 + threadIdx.x] = ssum;
  }
}

// ---- h2 = tanh(h1 @ W2[:32] + c2), f64, in place (per-thread addresses) ----
__global__ __launch_bounds__(256, 2) void h2_kernel(const double* __restrict__ hin,
                                                    const float* __restrict__ W2,
                                                    const double* __restrict__ c2,
                                                    double* __restrict__ hout,
                                                    double* __restrict__ ps_h) {
  __shared__ double Wl[32 * 32];
  __shared__ double ws[4 * 32];
  for (int i = threadIdx.x; i < 32 * 32; i += 256) Wl[i] = (double)W2[i];
  __syncthreads();
  const double* x = hin + (size_t)blockIdx.x * 8192 + threadIdx.x;
  double acc[32];
#pragma unroll
  for (int k = 0; k < 32; ++k) acc[k] = c2[k];
#pragma unroll 4
  for (int j = 0; j < 32; ++j) {
    double xj = x[j * 256];                 // 512B coalesced per wave
#pragma unroll
    for (int k = 0; k < 32; ++k) acc[k] += xj * Wl[j * 32 + k];
  }
  double* o = hout + (size_t)blockIdx.x * 8192 + threadIdx.x;
#pragma unroll
  for (int k = 0; k < 32; ++k) { acc[k] = tanh64(acc[k]); o[k * 256] = acc[k]; }
  int lane = threadIdx.x & 63, wave = threadIdx.x >> 6;
#pragma unroll
  for (int k = 0; k < 32; ++k) {
    double v = acc[k];
    v += __shfl_down(v, 32, 64); v += __shfl_down(v, 16, 64);
    v += __shfl_down(v, 8, 64);  v += __shfl_down(v, 4, 64);
    v += __shfl_down(v, 2, 64);  v += __shfl_down(v, 1, 64);
    if (lane == 0) ws[wave * 32 + k] = v;
  }
  __syncthreads();
  if (threadIdx.x < 32) {
    double ssum = ws[threadIdx.x] + ws[32 + threadIdx.x] + ws[64 + threadIdx.x] +
                  ws[96 + threadIdx.x];
    ps_h[blockIdx.x * 32 + threadIdx.x] = ssum;
  }
}

// ---- g, alpha, hard_alpha, per-block last-fired, logprob partials ----
__global__ __launch_bounds__(256, 2) void out_kernel(const double* __restrict__ h,
                                                     const float* __restrict__ W3,
                                                     const double* __restrict__ c3,
                                                     const float* __restrict__ u,
                                                     float* __restrict__ g, float* __restrict__ ha,
                                                     int* __restrict__ lastf,
                                                     double* __restrict__ lp_part) {
  __shared__ double Wl[32 * 17];
  __shared__ double sm[256];
  __shared__ unsigned long long wm[4];
  for (int i = threadIdx.x; i < 32 * 17; i += 256) {
    int j = i / 17, k = i - j * 17;
    Wl[i] = (double)W3[j * 49 + 32 + k];
  }
  __syncthreads();
  long t = (long)blockIdx.x * 256 + threadIdx.x;
  const double* x = h + (size_t)blockIdx.x * 8192 + threadIdx.x;
  double acc[17];
#pragma unroll
  for (int k = 0; k < 17; ++k) acc[k] = c3[k];
#pragma unroll 4
  for (int j = 0; j < 32; ++j) {
    double xj = x[j * 256];                 // 512B coalesced per wave
#pragma unroll
    for (int k = 0; k < 17; ++k) acc[k] += xj * Wl[j * 17 + k];
  }
  float4* g4 = (float4*)(g + t * 16);
  float4 o0, o1, o2, o3;
  o0.x = (float)acc[0];  o0.y = (float)acc[1];  o0.z = (float)acc[2];  o0.w = (float)acc[3];
  o1.x = (float)acc[4];  o1.y = (float)acc[5];  o1.z = (float)acc[6];  o1.w = (float)acc[7];
  o2.x = (float)acc[8];  o2.y = (float)acc[9];  o2.z = (float)acc[10]; o2.w = (float)acc[11];
  o3.x = (float)acc[12]; o3.y = (float)acc[13]; o3.z = (float)acc[14]; o3.w = (float)acc[15];
  g4[0] = o0; g4[1] = o1; g4[2] = o2; g4[3] = o3;
  double l = acc[16];
  double lc = fmin(fmax(l, -700.0), 700.0);
  double alpha = 1.0 / (1.0 + exp64(-lc));
  bool fired = ((double)u[t]) < alpha;
  ha[t] = fired ? 1.f : 0.f;
  float lf = (float)l;                      // log-prob only feeds the loss: f32 ok
  sm[threadIdx.x] = (double)(fired ? -spf32(-lf) : -spf32(lf));
  unsigned long long bm = __ballot(fired ? 1 : 0);
  if ((threadIdx.x & 63) == 0) wm[threadIdx.x >> 6] = bm;
  __syncthreads();
  for (int off = 128; off > 0; off >>= 1) {
    if (threadIdx.x < off) sm[threadIdx.x] += sm[threadIdx.x + off];
    __syncthreads();
  }
  if (threadIdx.x == 0) {
    lp_part[blockIdx.x] = sm[0];
    int last = -1;
#pragma unroll
    for (int w = 3; w >= 0; --w) {
      if (last < 0 && wm[w])
        last = (int)((long)blockIdx.x * 256 + w * 64 + (63 - __builtin_clzll(wm[w])));
    }
    lastf[blockIdx.x] = last;
  }
}

// ---- exclusive max-scan over per-block last-fired indices ----
__global__ __launch_bounds__(1024) void carry_scan(const int* __restrict__ lastf,
                                                   int* __restrict__ carry, int n) {
  __shared__ int sm[1024];
  int tid = threadIdx.x;
  sm[tid] = (tid < n) ? lastf[tid] : -1;
  __syncthreads();
  for (int off = 1; off < n; off <<= 1) {
    int v = sm[tid];
    int o = (tid >= off) ? sm[tid - off] : -1;
    __syncthreads();
    sm[tid] = v > o ? v : o;
    __syncthreads();
  }
  if (tid < n) carry[tid] = (tid == 0) ? -1 : sm[tid - 1];
}

// ---- scan-combine, hard_g gather, decode MLP, logits, BCE partials ----
__global__ __launch_bounds__(256, 2) void decode_kernel(
    const float* __restrict__ s, const float* __restrict__ a, const float* __restrict__ g,
    const float* __restrict__ Wp1, const float* __restrict__ bp1, const float* __restrict__ Wp2,
    const float* __restrict__ bp2, const float* __restrict__ ha, const int* __restrict__ carry,
    float* __restrict__ logits, float* __restrict__ hardg, double* __restrict__ rc_part) {
  __shared__ float W1l[80 * 32];
  __shared__ float W2l[32 * 16];
  __shared__ int wlast[4];
  __shared__ double sm[256];
  long t = (long)blockIdx.x * 256 + threadIdx.x;
  bool fired = ha[t] > 0.5f;
  unsigned long long m = __ballot(fired ? 1 : 0);
  int wave = threadIdx.x >> 6, lane = threadIdx.x & 63;
  if (lane == 0)
    wlast[wave] = m ? (int)((long)blockIdx.x * 256 + wave * 64 + (63 - __builtin_clzll(m))) : -1;
  for (int i = threadIdx.x; i < 80 * 32; i += 256) W1l[i] = Wp1[i];
  for (int i = threadIdx.x; i < 32 * 16; i += 256) W2l[i] = Wp2[i];
  __syncthreads();
  unsigned long long pm = m & (~0ULL >> (63 - lane));
  int idx = pm ? (int)((long)blockIdx.x * 256 + wave * 64 + (63 - __builtin_clzll(pm))) : -1;
#pragma unroll
  for (int w = 0; w < 4; ++w)
    if (w < wave && wlast[w] > idx) idx = wlast[w];
  int cr = carry[blockIdx.x];
  if (cr > idx) idx = cr;
  float hg[16];
  if (idx >= 0) {
    const float4* g4 = (const float4*)(g + (long)idx * 16);
    float4 v0 = g4[0], v1 = g4[1], v2 = g4[2], v3 = g4[3];
    hg[0] = v0.x; hg[1] = v0.y; hg[2] = v0.z; hg[3] = v0.w;
    hg[4] = v1.x; hg[5] = v1.y; hg[6] = v1.z; hg[7] = v1.w;
    hg[8] = v2.x; hg[9] = v2.y; hg[10] = v2.z; hg[11] = v2.w;
    hg[12] = v3.x; hg[13] = v3.y; hg[14] = v3.z; hg[15] = v3.w;
  } else {
#pragma unroll
    for (int k = 0; k < 16; ++k) hg[k] = 0.f;
  }
#pragma unroll
  for (int k = 0; k < 16; ++k) hardg[t * 16 + k] = hg[k];   // d_out+… is 4B aligned only
  float acc[32];
#pragma unroll
  for (int k = 0; k < 32; ++k) acc[k] = bp1[k];
  const float4* s4 = (const float4*)(s + t * 64);
#pragma unroll 4
  for (int q = 0; q < 16; ++q) {
    float4 v = s4[q];
    const float* w = &W1l[(q * 4) * 32];
#pragma unroll
    for (int k = 0; k < 32; ++k)
      acc[k] += v.x * w[k] + v.y * w[32 + k] + v.z * w[64 + k] + v.w * w[96 + k];
  }
#pragma unroll
  for (int j = 0; j < 16; ++j) {
    float xj = hg[j];
    const float* w = &W1l[(64 + j) * 32];
#pragma unroll
    for (int k = 0; k < 32; ++k) acc[k] += xj * w[k];
  }
#pragma unroll
  for (int k = 0; k < 32; ++k) acc[k] = tanhf(acc[k]);
  float lg[16];
#pragma unroll
  for (int k = 0; k < 16; ++k) lg[k] = bp2[k];
#pragma unroll
  for (int j = 0; j < 32; ++j) {
    float hj = acc[j];
    const float* w = &W2l[j * 16];
#pragma unroll
    for (int k = 0; k < 16; ++k) lg[k] += hj * w[k];
  }
#pragma unroll
  for (int k = 0; k < 16; ++k) logits[t * 16 + k] = lg[k];
  const float4* a4 = (const float4*)(a + t * 16);
  double rs = 0.0;
#pragma unroll
  for (int q = 0; q < 4; ++q) {
    float4 av = a4[q];
    float l0 = lg[q * 4], l1 = lg[q * 4 + 1], l2 = lg[q * 4 + 2], l3 = lg[q * 4 + 3];
    rs += (double)(av.x * spf32(-l0) + (1.f - av.x) * spf32(l0));
    rs += (double)(av.y * spf32(-l1) + (1.f - av.y) * spf32(l1));
    rs += (double)(av.z * spf32(-l2) + (1.f - av.z) * spf32(l2));
    rs += (double)(av.w * spf32(-l3) + (1.f - av.w) * spf32(l3));
  }
  sm[threadIdx.x] = rs;
  __syncthreads();
  for (int off = 128; off > 0; off >>= 1) {
    if (threadIdx.x < off) sm[threadIdx.x] += sm[threadIdx.x + off];
    __syncthreads();
  }
  if (threadIdx.x == 0) rc_part[blockIdx.x] = sm[0];
}

// ---- loss = mean(recon) * (1 + mean(log_probs)) ----
__global__ __launch_bounds__(256) void finalize(const double* __restrict__ lp_part,
                                                const double* __restrict__ rc_part, int nb,
                                                double invT, float* __restrict__ out0) {
  __shared__ double s1[256], s2[256];
  int tid = threadIdx.x;
  double a1 = 0, a2 = 0;
  for (int i = tid; i < nb; i += 256) { a1 += lp_part[i]; a2 += rc_part[i]; }
  s1[tid] = a1; s2[tid] = a2;
  __syncthreads();
  for (int off = 128; off > 0; off >>= 1) {
    if (tid < off) { s1[tid] += s1[tid + off]; s2[tid] += s2[tid + off]; }
    __syncthreads();
  }
  if (tid == 0) {
    double R = s1[0] * invT;            // mean log_probs over T
    double M = s2[0] * invT / 16.0;     // mean recon over T*16
    out0[0] = (float)(M + R * M);
  }
}

extern "C" void kernel_launch(void* const* d_in, const int* in_sizes, int n_in,
                              void* d_out, int out_size, void* d_ws, size_t ws_size,
                              hipStream_t stream) {
  const float* s   = (const float*)d_in[0];
  const float* a   = (const float*)d_in[1];
  const float* u   = (const float*)d_in[2];
  const float* W1  = (const float*)d_in[3];
  const float* b1  = (const float*)d_in[4];
  const float* W2  = (const float*)d_in[5];
  const float* b2  = (const float*)d_in[6];
  const float* W3  = (const float*)d_in[7];
  const float* b3  = (const float*)d_in[8];
  const float* Wp1 = (const float*)d_in[9];
  const float* bp1 = (const float*)d_in[10];
  const float* Wp2 = (const float*)d_in[11];
  const float* bp2 = (const float*)d_in[12];

  const double invT = 1.0 / (double)TT;

  // workspace carve (f64 first for alignment)
  double* h      = (double*)d_ws;                 // TT*32 (h1, then h2 in place)
  double* ps_s   = h + (size_t)TT * 32;           // NBR*64
  double* ps_a   = ps_s + (size_t)NBR * 64;       // NBR*16
  double* ps_h   = ps_a + (size_t)NBR * 16;       // NBT*32 (h1 partials, then h2)
  double* c1     = ps_h + (size_t)NBT * 32;       // 32
  double* c2     = c1 + 32;                       // 32
  double* c3     = c2 + 32;                       // 24 (17 used)
  double* lp_part= c3 + 24;                       // NBT
  double* rc_part= lp_part + NBT;                 // NBT
  float*  g      = (float*)(rc_part + NBT);       // TT*16
  int*    lastf  = (int*)(g + (size_t)TT * 16);   // NBT
  int*    carry  = lastf + NBT;                   // NBT

  float* out    = (float*)d_out;
  float* loss   = out;
  float* logits = out + 1;
  float* ha     = out + 1 + (size_t)TT * 16;
  float* hg     = ha + TT;

  reduce_cols<64><<<NBR, 256, 0, stream>>>(s, ps_s);
  reduce_cols<16><<<NBR, 256, 0, stream>>>(a, ps_a);
  prep1<<<1, 640, 0, stream>>>(ps_s, ps_a, W1, b1, invT, c1);
  h1_kernel<<<NBT, 256, 0, stream>>>(s, a, W1, c1, h, ps_h);
  prep2<<<1, 256, 0, stream>>>(ps_h, W2, b2, invT, c2);
  h2_kernel<<<NBT, 256, 0, stream>>>(h, W2, c2, h, ps_h);
  prep3<<<1, 256, 0, stream>>>(ps_h, W3, b3, invT, c3);
  out_kernel<<<NBT, 256, 0, stream>>>(h, W3, c3, u, g, ha, lastf, lp_part);
  carry_scan<<<1, NBT, 0, stream>>>(lastf, carry, NBT);
  decode_kernel<<<NBT, 256, 0, stream>>>(s, a, g, Wp1, bp1, Wp2, bp2, ha, carry,
                                         logits, hg, rc_part);
  finalize<<<1, 256, 0, stream>>>(lp_part, rc_part, NBT, invT, loss);
}

// Round 6
// 321.177 us; speedup vs baseline: 2.0737x; 1.7997x over previous
//
#include <hip/hip_runtime.h>
#include <math.h>

// AlphaSegmenter: GNN encode (f64 path for exact Bernoulli decisions) ->
// Bernoulli threshold -> segmented carry scan -> decode MLP (f32) -> BCE loss.
// Outputs: [loss(1), logits(T*16), hard_alpha(T), hard_g(T*16)] as f32.
// R2: capped unrolling (decode spilled 6.7GB -> 786us).
// R3: parallel preps + fused h-column-sums (786->470us).
// R4: h relayout [block][col][256] (coalesced) but WRITE exploded to 1GB.
// R5: full unroll + inline exp64 (no OCML f64) fixed h1 (403->~60us).
// R6: decode STILL spilled (FETCH 377/WRITE 355 MB vs 97/32 ideal, VGPR=128):
//     hg[16] was live across the whole 2048-FMA s-loop. Reorder: consume hg
//     into acc BEFORE the s-loop (FP-order change ~1e-6 << 6e-2 threshold),
//     non-divergent gather. Peak live regs ~60 -> no spill.

#define TT 262144
#define NBT 1024   // TT/256 tile blocks
#define NBR 512    // reduction blocks for s,a

__device__ __forceinline__ float spf32(float x) {             // softplus f32
  return fmaxf(x, 0.f) + log1pf(expf(-fabsf(x)));
}

// ---- inline f64 exp: Cody-Waite + degree-12 Horner, |x| <= 700 ----
__device__ __forceinline__ double exp64(double x) {
  const double LOG2E  = 1.4426950408889634074;
  const double LN2_HI = 6.93147180369123816490e-01;
  const double LN2_LO = 1.90821492927058770002e-10;
  double kd = rint(x * LOG2E);
  double r  = fma(-kd, LN2_HI, x);
  r = fma(-kd, LN2_LO, r);
  double p = 2.08767569878681e-9;                 // 1/12!
  p = fma(p, r, 2.505210838544172e-8);            // 1/11!
  p = fma(p, r, 2.755731922398589e-7);            // 1/10!
  p = fma(p, r, 2.7557319223985893e-6);           // 1/9!
  p = fma(p, r, 2.48015873015873e-5);             // 1/8!
  p = fma(p, r, 1.984126984126984e-4);            // 1/7!
  p = fma(p, r, 1.388888888888889e-3);            // 1/6!
  p = fma(p, r, 8.333333333333333e-3);            // 1/5!
  p = fma(p, r, 4.1666666666666664e-2);           // 1/4!
  p = fma(p, r, 1.6666666666666666e-1);           // 1/3!
  p = fma(p, r, 0.5);
  p = fma(p, r, 1.0);
  p = fma(p, r, 1.0);
  int k = (int)kd;
  long long sb = ((long long)(k + 1023)) << 52;   // 2^k
  return p * __longlong_as_double(sb);
}

__device__ __forceinline__ double tanh64(double x) {
  double ax = fmin(fabs(x), 19.0);                // tanh(19) rounds to <1ulp of 1
  double e = exp64(2.0 * ax);
  double t = 1.0 - 2.0 / (e + 1.0);
  return x >= 0.0 ? t : -t;
}

// ---- deterministic column-sum: in [T,C] -> partials [NBR][C] (f64) ----
template <int C>
__global__ __launch_bounds__(256) void reduce_cols(const float* __restrict__ in,
                                                   double* __restrict__ part) {
  const int rpb = 256 / C;
  int col = threadIdx.x & (C - 1);
  int sub = threadIdx.x / C;
  long row0 = (long)blockIdx.x * rpb + sub;
  long stride = (long)NBR * rpb;
  double acc = 0.0;
  for (long r = row0; r < TT; r += stride) acc += (double)in[r * C + col];
  __shared__ double sm[256];
  sm[threadIdx.x] = acc;
  __syncthreads();
  if (threadIdx.x < C) {
    double s = 0.0;
#pragma unroll
    for (int i = 0; i < rpb; ++i) s += sm[i * C + threadIdx.x];  // fixed order
    part[(long)blockIdx.x * C + threadIdx.x] = s;
  }
}

// ---- c1 = b1 + mean_x @ W1[80:160]; parallel tree over [512][64|16] ----
__global__ __launch_bounds__(640) void prep1(const double* __restrict__ ps_s,
                                             const double* __restrict__ ps_a,
                                             const float* __restrict__ W1,
                                             const float* __restrict__ b1,
                                             double invT, double* __restrict__ c1) {
  __shared__ double partial[80][8];
  __shared__ double mx[80];
  int tid = threadIdx.x;
  int col = tid >> 3, sub = tid & 7;   // 80 cols x 8 threads
  double ssum = 0.0;
  if (col < 64) {
#pragma unroll
    for (int i = 0; i < 64; ++i) ssum += ps_s[(sub * 64 + i) * 64 + col];
  } else {
    int c = col - 64;
#pragma unroll
    for (int i = 0; i < 64; ++i) ssum += ps_a[(sub * 64 + i) * 16 + c];
  }
  partial[col][sub] = ssum;
  __syncthreads();
  if (tid < 80) {
    double s = 0.0;
#pragma unroll
    for (int i = 0; i < 8; ++i) s += partial[tid][i];  // fixed order
    mx[tid] = s * invT;
  }
  __syncthreads();
  if (tid < 32) {
    double acc = (double)b1[tid];
    for (int j = 0; j < 80; ++j) acc += mx[j] * (double)W1[(80 + j) * 32 + tid];
    c1[tid] = acc;
  }
}

// ---- c2 = b2 + mean_h1 @ W2[32:64]; parallel tree over [1024][32] ----
__global__ __launch_bounds__(256) void prep2(const double* __restrict__ ps,
                                             const float* __restrict__ W2,
                                             const float* __restrict__ b2,
                                             double invT, double* __restrict__ c2) {
  __shared__ double partial[32][8];
  __shared__ double mh[32];
  int tid = threadIdx.x;
  int col = tid >> 3, sub = tid & 7;   // 32 cols x 8 threads, 128 each
  double ssum = 0.0;
#pragma unroll
  for (int i = 0; i < 128; ++i) ssum += ps[(sub * 128 + i) * 32 + col];
  partial[col][sub] = ssum;
  __syncthreads();
  if (tid < 32) {
    double s = 0.0;
#pragma unroll
    for (int i = 0; i < 8; ++i) s += partial[tid][i];
    mh[tid] = s * invT;
  }
  __syncthreads();
  if (tid < 32) {
    double acc = (double)b2[tid];
    for (int j = 0; j < 32; ++j) acc += mh[j] * (double)W2[(32 + j) * 32 + tid];
    c2[tid] = acc;
  }
}

// ---- c3[k] = b3[32+k] + mean_h2 @ W3[32:64, 32+k], k=0..16 ----
__global__ __launch_bounds__(256) void prep3(const double* __restrict__ ps,
                                             const float* __restrict__ W3,
                                             const float* __restrict__ b3,
                                             double invT, double* __restrict__ c3) {
  __shared__ double partial[32][8];
  __shared__ double mh[32];
  int tid = threadIdx.x;
  int col = tid >> 3, sub = tid & 7;
  double ssum = 0.0;
#pragma unroll
  for (int i = 0; i < 128; ++i) ssum += ps[(sub * 128 + i) * 32 + col];
  partial[col][sub] = ssum;
  __syncthreads();
  if (tid < 32) {
    double s = 0.0;
#pragma unroll
    for (int i = 0; i < 8; ++i) s += partial[tid][i];
    mh[tid] = s * invT;
  }
  __syncthreads();
  if (tid < 17) {
    double acc = (double)b3[32 + tid];
    for (int j = 0; j < 32; ++j) acc += mh[j] * (double)W3[(32 + j) * 49 + 32 + tid];
    c3[tid] = acc;
  }
}

// h layout: element (block b, col k, row r in 0..255) at h[b*8192 + k*256 + r]

// ---- h1 = tanh([s,a] @ W1[:80] + c1), f64; emits per-block col sums ----
__global__ __launch_bounds__(256, 2) void h1_kernel(const float* __restrict__ s,
                                                    const float* __restrict__ a,
                                                    const float* __restrict__ W1,
                                                    const double* __restrict__ c1,
                                                    double* __restrict__ h,
                                                    double* __restrict__ ps_h) {
  __shared__ double Wl[80 * 32];
  __shared__ double ws[4 * 32];
  for (int i = threadIdx.x; i < 80 * 32; i += 256) Wl[i] = (double)W1[i];
  __syncthreads();
  long t = (long)blockIdx.x * 256 + threadIdx.x;
  double acc[32];
#pragma unroll
  for (int k = 0; k < 32; ++k) acc[k] = c1[k];
  const float4* s4 = (const float4*)(s + t * 64);
#pragma unroll 2
  for (int q = 0; q < 16; ++q) {
    float4 v = s4[q];
    const double* w = &Wl[(q * 4) * 32];
    double x0 = (double)v.x, x1 = (double)v.y, x2 = (double)v.z, x3 = (double)v.w;
#pragma unroll
    for (int k = 0; k < 32; ++k)
      acc[k] += x0 * w[k] + x1 * w[32 + k] + x2 * w[64 + k] + x3 * w[96 + k];
  }
  const float4* a4 = (const float4*)(a + t * 16);
#pragma unroll 2
  for (int q = 0; q < 4; ++q) {
    float4 v = a4[q];
    const double* w = &Wl[(64 + q * 4) * 32];
    double x0 = (double)v.x, x1 = (double)v.y, x2 = (double)v.z, x3 = (double)v.w;
#pragma unroll
    for (int k = 0; k < 32; ++k)
      acc[k] += x0 * w[k] + x1 * w[32 + k] + x2 * w[64 + k] + x3 * w[96 + k];
  }
  double* o = h + (size_t)blockIdx.x * 8192 + threadIdx.x;
#pragma unroll
  for (int k = 0; k < 32; ++k) { acc[k] = tanh64(acc[k]); o[k * 256] = acc[k]; }
  int lane = threadIdx.x & 63, wave = threadIdx.x >> 6;
#pragma unroll
  for (int k = 0; k < 32; ++k) {
    double v = acc[k];
    v += __shfl_down(v, 32, 64); v += __shfl_down(v, 16, 64);
    v += __shfl_down(v, 8, 64);  v += __shfl_down(v, 4, 64);
    v += __shfl_down(v, 2, 64);  v += __shfl_down(v, 1, 64);
    if (lane == 0) ws[wave * 32 + k] = v;
  }
  __syncthreads();
  if (threadIdx.x < 32) {
    double ssum = ws[threadIdx.x] + ws[32 + threadIdx.x] + ws[64 + threadIdx.x] +
                  ws[96 + threadIdx.x];
    ps_h[blockIdx.x * 32 + threadIdx.x] = ssum;
  }
}

// ---- h2 = tanh(h1 @ W2[:32] + c2), f64, in place (per-thread addresses) ----
__global__ __launch_bounds__(256, 2) void h2_kernel(const double* __restrict__ hin,
                                                    const float* __restrict__ W2,
                                                    const double* __restrict__ c2,
                                                    double* __restrict__ hout,
                                                    double* __restrict__ ps_h) {
  __shared__ double Wl[32 * 32];
  __shared__ double ws[4 * 32];
  for (int i = threadIdx.x; i < 32 * 32; i += 256) Wl[i] = (double)W2[i];
  __syncthreads();
  const double* x = hin + (size_t)blockIdx.x * 8192 + threadIdx.x;
  double acc[32];
#pragma unroll
  for (int k = 0; k < 32; ++k) acc[k] = c2[k];
#pragma unroll 4
  for (int j = 0; j < 32; ++j) {
    double xj = x[j * 256];                 // 512B coalesced per wave
#pragma unroll
    for (int k = 0; k < 32; ++k) acc[k] += xj * Wl[j * 32 + k];
  }
  double* o = hout + (size_t)blockIdx.x * 8192 + threadIdx.x;
#pragma unroll
  for (int k = 0; k < 32; ++k) { acc[k] = tanh64(acc[k]); o[k * 256] = acc[k]; }
  int lane = threadIdx.x & 63, wave = threadIdx.x >> 6;
#pragma unroll
  for (int k = 0; k < 32; ++k) {
    double v = acc[k];
    v += __shfl_down(v, 32, 64); v += __shfl_down(v, 16, 64);
    v += __shfl_down(v, 8, 64);  v += __shfl_down(v, 4, 64);
    v += __shfl_down(v, 2, 64);  v += __shfl_down(v, 1, 64);
    if (lane == 0) ws[wave * 32 + k] = v;
  }
  __syncthreads();
  if (threadIdx.x < 32) {
    double ssum = ws[threadIdx.x] + ws[32 + threadIdx.x] + ws[64 + threadIdx.x] +
                  ws[96 + threadIdx.x];
    ps_h[blockIdx.x * 32 + threadIdx.x] = ssum;
  }
}

// ---- g, alpha, hard_alpha, per-block last-fired, logprob partials ----
__global__ __launch_bounds__(256, 2) void out_kernel(const double* __restrict__ h,
                                                     const float* __restrict__ W3,
                                                     const double* __restrict__ c3,
                                                     const float* __restrict__ u,
                                                     float* __restrict__ g, float* __restrict__ ha,
                                                     int* __restrict__ lastf,
                                                     double* __restrict__ lp_part) {
  __shared__ double Wl[32 * 17];
  __shared__ double sm[256];
  __shared__ unsigned long long wm[4];
  for (int i = threadIdx.x; i < 32 * 17; i += 256) {
    int j = i / 17, k = i - j * 17;
    Wl[i] = (double)W3[j * 49 + 32 + k];
  }
  __syncthreads();
  long t = (long)blockIdx.x * 256 + threadIdx.x;
  const double* x = h + (size_t)blockIdx.x * 8192 + threadIdx.x;
  double acc[17];
#pragma unroll
  for (int k = 0; k < 17; ++k) acc[k] = c3[k];
#pragma unroll 4
  for (int j = 0; j < 32; ++j) {
    double xj = x[j * 256];                 // 512B coalesced per wave
#pragma unroll
    for (int k = 0; k < 17; ++k) acc[k] += xj * Wl[j * 17 + k];
  }
  float4* g4 = (float4*)(g + t * 16);
  float4 o0, o1, o2, o3;
  o0.x = (float)acc[0];  o0.y = (float)acc[1];  o0.z = (float)acc[2];  o0.w = (float)acc[3];
  o1.x = (float)acc[4];  o1.y = (float)acc[5];  o1.z = (float)acc[6];  o1.w = (float)acc[7];
  o2.x = (float)acc[8];  o2.y = (float)acc[9];  o2.z = (float)acc[10]; o2.w = (float)acc[11];
  o3.x = (float)acc[12]; o3.y = (float)acc[13]; o3.z = (float)acc[14]; o3.w = (float)acc[15];
  g4[0] = o0; g4[1] = o1; g4[2] = o2; g4[3] = o3;
  double l = acc[16];
  double lc = fmin(fmax(l, -700.0), 700.0);
  double alpha = 1.0 / (1.0 + exp64(-lc));
  bool fired = ((double)u[t]) < alpha;
  ha[t] = fired ? 1.f : 0.f;
  float lf = (float)l;                      // log-prob only feeds the loss: f32 ok
  sm[threadIdx.x] = (double)(fired ? -spf32(-lf) : -spf32(lf));
  unsigned long long bm = __ballot(fired ? 1 : 0);
  if ((threadIdx.x & 63) == 0) wm[threadIdx.x >> 6] = bm;
  __syncthreads();
  for (int off = 128; off > 0; off >>= 1) {
    if (threadIdx.x < off) sm[threadIdx.x] += sm[threadIdx.x + off];
    __syncthreads();
  }
  if (threadIdx.x == 0) {
    lp_part[blockIdx.x] = sm[0];
    int last = -1;
#pragma unroll
    for (int w = 3; w >= 0; --w) {
      if (last < 0 && wm[w])
        last = (int)((long)blockIdx.x * 256 + w * 64 + (63 - __builtin_clzll(wm[w])));
    }
    lastf[blockIdx.x] = last;
  }
}

// ---- exclusive max-scan over per-block last-fired indices ----
__global__ __launch_bounds__(1024) void carry_scan(const int* __restrict__ lastf,
                                                   int* __restrict__ carry, int n) {
  __shared__ int sm[1024];
  int tid = threadIdx.x;
  sm[tid] = (tid < n) ? lastf[tid] : -1;
  __syncthreads();
  for (int off = 1; off < n; off <<= 1) {
    int v = sm[tid];
    int o = (tid >= off) ? sm[tid - off] : -1;
    __syncthreads();
    sm[tid] = v > o ? v : o;
    __syncthreads();
  }
  if (tid < n) carry[tid] = (tid == 0) ? -1 : sm[tid - 1];
}

// ---- scan-combine, hard_g gather, decode MLP, logits, BCE partials ----
__global__ __launch_bounds__(256, 2) void decode_kernel(
    const float* __restrict__ s, const float* __restrict__ a, const float* __restrict__ g,
    const float* __restrict__ Wp1, const float* __restrict__ bp1, const float* __restrict__ Wp2,
    const float* __restrict__ bp2, const float* __restrict__ ha, const int* __restrict__ carry,
    float* __restrict__ logits, float* __restrict__ hardg, double* __restrict__ rc_part) {
  __shared__ float W1l[80 * 32];
  __shared__ float W2l[32 * 16];
  __shared__ int wlast[4];
  __shared__ double sm[256];
  long t = (long)blockIdx.x * 256 + threadIdx.x;
  bool fired = ha[t] > 0.5f;
  unsigned long long m = __ballot(fired ? 1 : 0);
  int wave = threadIdx.x >> 6, lane = threadIdx.x & 63;
  if (lane == 0)
    wlast[wave] = m ? (int)((long)blockIdx.x * 256 + wave * 64 + (63 - __builtin_clzll(m))) : -1;
  for (int i = threadIdx.x; i < 80 * 32; i += 256) W1l[i] = Wp1[i];
  for (int i = threadIdx.x; i < 32 * 16; i += 256) W2l[i] = Wp2[i];
  __syncthreads();
  unsigned long long pm = m & (~0ULL >> (63 - lane));
  int idx = pm ? (int)((long)blockIdx.x * 256 + wave * 64 + (63 - __builtin_clzll(pm))) : -1;
#pragma unroll
  for (int w = 0; w < 4; ++w)
    if (w < wave && wlast[w] > idx) idx = wlast[w];
  int cr = carry[blockIdx.x];
  if (cr > idx) idx = cr;
  // non-divergent gather: clamp index, mask result
  float msk = idx >= 0 ? 1.f : 0.f;
  const float4* g4 = (const float4*)(g + (long)(idx >= 0 ? idx : 0) * 16);
  float4 v0 = g4[0], v1 = g4[1], v2 = g4[2], v3 = g4[3];
  float hg0  = msk * v0.x, hg1  = msk * v0.y, hg2  = msk * v0.z, hg3  = msk * v0.w;
  float hg4  = msk * v1.x, hg5  = msk * v1.y, hg6  = msk * v1.z, hg7  = msk * v1.w;
  float hg8  = msk * v2.x, hg9  = msk * v2.y, hg10 = msk * v2.z, hg11 = msk * v2.w;
  float hg12 = msk * v3.x, hg13 = msk * v3.y, hg14 = msk * v3.z, hg15 = msk * v3.w;
  // store hard_g now (scalar stores; d_out region is only 4B aligned)
  hardg[t * 16 + 0]  = hg0;  hardg[t * 16 + 1]  = hg1;
  hardg[t * 16 + 2]  = hg2;  hardg[t * 16 + 3]  = hg3;
  hardg[t * 16 + 4]  = hg4;  hardg[t * 16 + 5]  = hg5;
  hardg[t * 16 + 6]  = hg6;  hardg[t * 16 + 7]  = hg7;
  hardg[t * 16 + 8]  = hg8;  hardg[t * 16 + 9]  = hg9;
  hardg[t * 16 + 10] = hg10; hardg[t * 16 + 11] = hg11;
  hardg[t * 16 + 12] = hg12; hardg[t * 16 + 13] = hg13;
  hardg[t * 16 + 14] = hg14; hardg[t * 16 + 15] = hg15;
  float acc[32];
  // consume hg FIRST so its registers die before the big s-loop
  // (FP sum-order differs from reference by ~1e-6 on logits; threshold 6e-2)
#pragma unroll
  for (int k = 0; k < 32; ++k) {
    float v = bp1[k];
    v += hg0  * W1l[(64 + 0)  * 32 + k];  v += hg1  * W1l[(64 + 1)  * 32 + k];
    v += hg2  * W1l[(64 + 2)  * 32 + k];  v += hg3  * W1l[(64 + 3)  * 32 + k];
    v += hg4  * W1l[(64 + 4)  * 32 + k];  v += hg5  * W1l[(64 + 5)  * 32 + k];
    v += hg6  * W1l[(64 + 6)  * 32 + k];  v += hg7  * W1l[(64 + 7)  * 32 + k];
    v += hg8  * W1l[(64 + 8)  * 32 + k];  v += hg9  * W1l[(64 + 9)  * 32 + k];
    v += hg10 * W1l[(64 + 10) * 32 + k];  v += hg11 * W1l[(64 + 11) * 32 + k];
    v += hg12 * W1l[(64 + 12) * 32 + k];  v += hg13 * W1l[(64 + 13) * 32 + k];
    v += hg14 * W1l[(64 + 14) * 32 + k];  v += hg15 * W1l[(64 + 15) * 32 + k];
    acc[k] = v;
  }
  const float4* s4 = (const float4*)(s + t * 64);
#pragma unroll 4
  for (int q = 0; q < 16; ++q) {
    float4 v = s4[q];
    const float* w = &W1l[(q * 4) * 32];
#pragma unroll
    for (int k = 0; k < 32; ++k)
      acc[k] += v.x * w[k] + v.y * w[32 + k] + v.z * w[64 + k] + v.w * w[96 + k];
  }
#pragma unroll
  for (int k = 0; k < 32; ++k) acc[k] = tanhf(acc[k]);
  float lg[16];
#pragma unroll
  for (int k = 0; k < 16; ++k) lg[k] = bp2[k];
#pragma unroll
  for (int j = 0; j < 32; ++j) {
    float hj = acc[j];
    const float* w = &W2l[j * 16];
#pragma unroll
    for (int k = 0; k < 16; ++k) lg[k] += hj * w[k];
  }
#pragma unroll
  for (int k = 0; k < 16; ++k) logits[t * 16 + k] = lg[k];
  const float4* a4 = (const float4*)(a + t * 16);
  double rs = 0.0;
#pragma unroll
  for (int q = 0; q < 4; ++q) {
    float4 av = a4[q];
    float l0 = lg[q * 4], l1 = lg[q * 4 + 1], l2 = lg[q * 4 + 2], l3 = lg[q * 4 + 3];
    rs += (double)(av.x * spf32(-l0) + (1.f - av.x) * spf32(l0));
    rs += (double)(av.y * spf32(-l1) + (1.f - av.y) * spf32(l1));
    rs += (double)(av.z * spf32(-l2) + (1.f - av.z) * spf32(l2));
    rs += (double)(av.w * spf32(-l3) + (1.f - av.w) * spf32(l3));
  }
  sm[threadIdx.x] = rs;
  __syncthreads();
  for (int off = 128; off > 0; off >>= 1) {
    if (threadIdx.x < off) sm[threadIdx.x] += sm[threadIdx.x + off];
    __syncthreads();
  }
  if (threadIdx.x == 0) rc_part[blockIdx.x] = sm[0];
}

// ---- loss = mean(recon) * (1 + mean(log_probs)) ----
__global__ __launch_bounds__(256) void finalize(const double* __restrict__ lp_part,
                                                const double* __restrict__ rc_part, int nb,
                                                double invT, float* __restrict__ out0) {
  __shared__ double s1[256], s2[256];
  int tid = threadIdx.x;
  double a1 = 0, a2 = 0;
  for (int i = tid; i < nb; i += 256) { a1 += lp_part[i]; a2 += rc_part[i]; }
  s1[tid] = a1; s2[tid] = a2;
  __syncthreads();
  for (int off = 128; off > 0; off >>= 1) {
    if (tid < off) { s1[tid] += s1[tid + off]; s2[tid] += s2[tid + off]; }
    __syncthreads();
  }
  if (tid == 0) {
    double R = s1[0] * invT;            // mean log_probs over T
    double M = s2[0] * invT / 16.0;     // mean recon over T*16
    out0[0] = (float)(M + R * M);
  }
}

extern "C" void kernel_launch(void* const* d_in, const int* in_sizes, int n_in,
                              void* d_out, int out_size, void* d_ws, size_t ws_size,
                              hipStream_t stream) {
  const float* s   = (const float*)d_in[0];
  const float* a   = (const float*)d_in[1];
  const float* u   = (const float*)d_in[2];
  const float* W1  = (const float*)d_in[3];
  const float* b1  = (const float*)d_in[4];
  const float* W2  = (const float*)d_in[5];
  const float* b2  = (const float*)d_in[6];
  const float* W3  = (const float*)d_in[7];
  const float* b3  = (const float*)d_in[8];
  const float* Wp1 = (const float*)d_in[9];
  const float* bp1 = (const float*)d_in[10];
  const float* Wp2 = (const float*)d_in[11];
  const float* bp2 = (const float*)d_in[12];

  const double invT = 1.0 / (double)TT;

  // workspace carve (f64 first for alignment)
  double* h      = (double*)d_ws;                 // TT*32 (h1, then h2 in place)
  double* ps_s   = h + (size_t)TT * 32;           // NBR*64
  double* ps_a   = ps_s + (size_t)NBR * 64;       // NBR*16
  double* ps_h   = ps_a + (size_t)NBR * 16;       // NBT*32 (h1 partials, then h2)
  double* c1     = ps_h + (size_t)NBT * 32;       // 32
  double* c2     = c1 + 32;                       // 32
  double* c3     = c2 + 32;                       // 24 (17 used)
  double* lp_part= c3 + 24;                       // NBT
  double* rc_part= lp_part + NBT;                 // NBT
  float*  g      = (float*)(rc_part + NBT);       // TT*16
  int*    lastf  = (int*)(g + (size_t)TT * 16);   // NBT
  int*    carry  = lastf + NBT;                   // NBT

  float* out    = (float*)d_out;
  float* loss   = out;
  float* logits = out + 1;
  float* ha     = out + 1 + (size_t)TT * 16;
  float* hg     = ha + TT;

  reduce_cols<64><<<NBR, 256, 0, stream>>>(s, ps_s);
  reduce_cols<16><<<NBR, 256, 0, stream>>>(a, ps_a);
  prep1<<<1, 640, 0, stream>>>(ps_s, ps_a, W1, b1, invT, c1);
  h1_kernel<<<NBT, 256, 0, stream>>>(s, a, W1, c1, h, ps_h);
  prep2<<<1, 256, 0, stream>>>(ps_h, W2, b2, invT, c2);
  h2_kernel<<<NBT, 256, 0, stream>>>(h, W2, c2, h, ps_h);
  prep3<<<1, 256, 0, stream>>>(ps_h, W3, b3, invT, c3);
  out_kernel<<<NBT, 256, 0, stream>>>(h, W3, c3, u, g, ha, lastf, lp_part);
  carry_scan<<<1, NBT, 0, stream>>>(lastf, carry, NBT);
  decode_kernel<<<NBT, 256, 0, stream>>>(s, a, g, Wp1, bp1, Wp2, bp2, ha, carry,
                                         logits, hg, rc_part);
  finalize<<<1, 256, 0, stream>>>(lp_part, rc_part, NBT, invT, loss);
}